// Round 6
// baseline (927.995 us; speedup 1.0000x reference)
//
#include <hip/hip_runtime.h>

typedef unsigned short u16;
typedef unsigned int u32;
typedef __bf16 bf16x8 __attribute__((ext_vector_type(8)));
typedef float f32x4 __attribute__((ext_vector_type(4)));

#define MFMA16(a, b, c) __builtin_amdgcn_mfma_f32_16x16x32_bf16(a, b, c, 0, 0, 0)

__device__ __forceinline__ u16 f2bf(float f) {
  u32 u = __builtin_bit_cast(u32, f);
  u32 r = u + 0x7fffu + ((u >> 16) & 1u);
  return (u16)(r >> 16);
}

__device__ __forceinline__ uint4 cvt8(const float4& a, const float4& b) {
  union { u16 h[8]; uint4 q; } u;
  u.h[0] = f2bf(a.x); u.h[1] = f2bf(a.y); u.h[2] = f2bf(a.z); u.h[3] = f2bf(a.w);
  u.h[4] = f2bf(b.x); u.h[5] = f2bf(b.y); u.h[6] = f2bf(b.z); u.h[7] = f2bf(b.w);
  return u.q;
}

// async global->LDS, 16B per lane; lds dst is wave-uniform base + lane*16
__device__ __forceinline__ void gload16(const u16* g, u16* l) {
  __builtin_amdgcn_global_load_lds(
      (const __attribute__((address_space(1))) u32*)g,
      (__attribute__((address_space(3))) u32*)l, 16, 0, 0);
}

// ---------------------------------------------------------------------------
// 256x256-tile bf16 MFMA GEMM — round-6: ONE barrier per K-tile, software-
// pipelined fragments. Round-5 post-mortem: intra-tile barriers made the
// schedule bulk-synchronous (read-burst drain exposed before every MFMA
// cluster, matrix pipe idle, 1 block/CU so no TLP cover) -> stuck at the
// measured 2-phase plateau (682 TF). Intra-tile barriers are NOT needed for
// correctness: all intra-tile ds_reads hit the published buffer; MFMA is
// register-only. So: per K-tile = [fenced publish barrier] then 4 clusters
// of 16 MFMA, with the NEXT cluster's 4-8 ds_read_b128 issued BEFORE each
// cluster (frag regs double-buffered; lgkmcnt retires in-order so the
// compiler waits only on the older group). Stage DMA for t+1: k0-group
// right after the barrier, k1-group mid-tile; single vmcnt(0) at tile end
// sits >=2 MFMA clusters (~1240cy) after the newest issue > 900cy HBM
// latency. Publish barrier is fence-wrapped (s_barrier is NoMem in LLVM);
// stage(t+1) targets buffer (t+1)&1, last read in tile t-1, protected by
// this tile's barrier.
// BK=64, 8 waves (512 thr, 2Mx4N), wave tile 128x64, acc[8][4].
// LDS [2 buf][2 k-half][256][32] u16 = 128 KB. Verified swizzle pair
// (0 conflicts measured): stage col scol=((l&3)^((l>>3)&3))*8, read at
// su=(quad^((lr>>1)&3))*8.
// Grid: 64 M-blocks x (N/256), groups of 16 M-blocks (A-sharers same XCD).
// C = A(MxK, lda) * W(NxK, ldb)^T, fused epilogues:
// MODE 0: +bias, store bf16               (qkv)
// MODE 1: +bias +aux0(x f32), store f32   (out_proj -> x1 in d_out)
// MODE 3: outF += 0.1*(acc + gb)          (adapter up -> y into d_out)
// MODE 4: +bias, QuickGELU, bf16          (c_fc -> h2)
// MODE 5: outF += acc (+bias if given)    (c_proj into d_out)
// ---------------------------------------------------------------------------
template <int MODE>
__global__ __launch_bounds__(512, 2) void gemm256_k(
    const u16* __restrict__ A, int lda,
    const u16* __restrict__ W, int ldb,
    const float* __restrict__ bias, const float* __restrict__ aux0,
    float* __restrict__ outF, u16* __restrict__ outB, int N, int K)
{
  __shared__ u16 As[2][2][8192];   // [buf][khalf][256 rows x 32 cols]
  __shared__ u16 Bs[2][2][8192];
  const int tid = threadIdx.x;
  const int nxb = N >> 8;
  const int gsz = nxb << 4;               // 16 M-blocks per group
  const int g = blockIdx.x / gsz;
  const int rem = blockIdx.x - g * gsz;
  const int m0 = ((g << 4) + (rem & 15)) * 256;
  const int n0 = (rem >> 4) * 256;
  const int w = tid >> 6, lane = tid & 63, lr = lane & 15, quad = lane >> 4;
  const int wr = (w >> 2) * 128, wc = (w & 3) * 64;

  f32x4 acc[8][4];
  #pragma unroll
  for (int i = 0; i < 8; i++)
    #pragma unroll
    for (int j = 0; j < 4; j++)
      #pragma unroll
      for (int r = 0; r < 4; r++) acc[i][j][r] = 0.f;

  // staging addresses (verified round 3/4)
  const int sr = w * 16 + (lane >> 2);
  const int scol = ((lane & 3) ^ ((lane >> 3) & 3)) * 8;
  const u16* gA0 = A + (long)(m0 + sr) * lda + scol;
  const u16* gA1 = gA0 + (long)128 * lda;
  const u16* gB0 = W + (long)(n0 + sr) * ldb + scol;
  const u16* gB1 = gB0 + (long)128 * ldb;
  const int lo = w << 9;                  // wave-uniform LDS base (u16)
  const int su = (quad ^ ((lr >> 1) & 3)) * 8;   // read-side swizzled slot

  auto rdA = [&](bf16x8* af, const u16* tile, int ih) {
    #pragma unroll
    for (int i2 = 0; i2 < 4; i2++)
      af[i2] = *(const bf16x8*)&tile[(wr + ih * 64 + i2 * 16 + lr) * 32 + su];
  };
  auto rdB4 = [&](bf16x8* bb, const u16* tile) {
    #pragma unroll
    for (int j = 0; j < 4; j++)
      bb[j] = *(const bf16x8*)&tile[(wc + j * 16 + lr) * 32 + su];
  };
  auto mm16 = [&](int ih, bf16x8* af, bf16x8* bb) {
    __builtin_amdgcn_s_setprio(1);
    #pragma unroll
    for (int i2 = 0; i2 < 4; i2++)
      #pragma unroll
      for (int j = 0; j < 4; j++)
        acc[ih * 4 + i2][j] = MFMA16(af[i2], bb[j], acc[ih * 4 + i2][j]);
    __builtin_amdgcn_s_setprio(0);
  };

  const int nt = K >> 6;                  // K-tiles of 64; >= 8 at all sites

  // prologue: stage K-tile 0 (4 chunks, 8 loads/wave), drain, publish
  gload16(gA0,      As[0][0] + lo); gload16(gA1,      As[0][0] + 4096 + lo);
  gload16(gB0,      Bs[0][0] + lo); gload16(gB1,      Bs[0][0] + 4096 + lo);
  gload16(gA0 + 32, As[0][1] + lo); gload16(gA1 + 32, As[0][1] + 4096 + lo);
  gload16(gB0 + 32, Bs[0][1] + lo); gload16(gB1 + 32, Bs[0][1] + 4096 + lo);
  asm volatile("s_waitcnt vmcnt(0)" ::: "memory");
  __syncthreads();

  for (int t = 0; t < nt; ++t) {
    const int cur = t & 1, nb = cur ^ 1;
    const bool more = (t + 1) < nt;
    const long kb = (long)(t + 1) * 64;
    const u16* A0 = As[cur][0]; const u16* A1 = As[cur][1];
    const u16* B0 = Bs[cur][0]; const u16* B1 = Bs[cur][1];
    bf16x8 afA[4], afB[4], bb0[4], bb1[4];

    // cluster-0 frags (only drain exposed per tile)
    rdB4(bb0, B0); rdA(afA, A0, 0);
    // stage next tile k0 early — max distance to the tile-end vmcnt
    if (more) {
      gload16(gA0 + kb, As[nb][0] + lo);
      gload16(gA1 + kb, As[nb][0] + 4096 + lo);
      gload16(gB0 + kb, Bs[nb][0] + lo);
      gload16(gB1 + kb, Bs[nb][0] + 4096 + lo);
    }
    rdA(afB, A0, 1);                 // cluster-1 frags in flight under c0
    mm16(0, afA, bb0);               // c0: (k0, ih0)
    rdB4(bb1, B1); rdA(afA, A1, 0);  // cluster-2 frags in flight under c1
    if (more) {
      gload16(gA0 + kb + 32, As[nb][1] + lo);
      gload16(gA1 + kb + 32, As[nb][1] + 4096 + lo);
      gload16(gB0 + kb + 32, Bs[nb][1] + lo);
      gload16(gB1 + kb + 32, Bs[nb][1] + 4096 + lo);
    }
    mm16(1, afB, bb0);               // c1: (k0, ih1)
    rdA(afB, A1, 1);                 // cluster-3 frags in flight under c2
    mm16(0, afA, bb1);               // c2: (k1, ih0)
    mm16(1, afB, bb1);               // c3: (k1, ih1)

    // publish: own DMA retired (issued >=2 clusters ago), then barrier.
    // fences pin DMA issue above / next-tile reads below (s_barrier is NoMem).
    asm volatile("s_waitcnt vmcnt(0)" ::: "memory");
    __builtin_amdgcn_s_barrier();
    asm volatile("" ::: "memory");
  }

  #pragma unroll
  for (int i = 0; i < 8; i++) {
    #pragma unroll
    for (int j = 0; j < 4; j++) {
      #pragma unroll
      for (int r = 0; r < 4; r++) {
        const int gm = m0 + wr + i * 16 + quad * 4 + r;
        const int gn = n0 + wc + j * 16 + lr;
        const long oidx = (long)gm * N + gn;
        float v = acc[i][j][r];
        if constexpr (MODE == 0) {
          v += bias[gn];
          outB[oidx] = f2bf(v);
        } else if constexpr (MODE == 1) {
          v += bias[gn] + aux0[oidx];
          outF[oidx] = v;
        } else if constexpr (MODE == 3) {
          outF[oidx] += 0.1f * (v + aux0[(gm & 63) * 1024 + gn]);
        } else if constexpr (MODE == 4) {
          v += bias[gn];
          float e = __expf(-1.702f * v);
          v = v * __builtin_amdgcn_rcpf(1.f + e);
          outB[oidx] = f2bf(v);
        } else {
          if (bias) v += bias[gn];
          outF[oidx] += v;
        }
      }
    }
  }
}

// ---------------------------------------------------------------------------
// Adapter-down GEMM (proven round-1/2 path): 128x128 tile, A f32 convert-in-
// staging, relu + gate epilogue. Small (N=512, K=1024) — not worth porting.
// ---------------------------------------------------------------------------
__global__ __launch_bounds__(256) void gemm_down_k(
    const float* __restrict__ Af, int lda,
    const u16* __restrict__ W, int ldb,
    const float* __restrict__ bias, const float* __restrict__ gates,
    u16* __restrict__ outB, int N, int K)
{
  __shared__ u16 As[2][128 * 32];
  __shared__ u16 Bs[2][128 * 32];
  const int tid = threadIdx.x;
  const int nxb = gridDim.x >> 7;
  const int gsz = nxb << 5;
  const int g = blockIdx.x / gsz;
  const int rem = blockIdx.x - g * gsz;
  const int m0 = ((g << 5) + (rem & 31)) * 128;
  const int n0 = (rem >> 5) * 128;
  const int w = tid >> 6, lane = tid & 63, lr = lane & 15, quad = lane >> 4;
  const int wm = (w >> 1) * 64, wn = (w & 1) * 64;

  f32x4 acc[4][4];
  #pragma unroll
  for (int i = 0; i < 4; i++)
    #pragma unroll
    for (int j = 0; j < 4; j++)
      #pragma unroll
      for (int r = 0; r < 4; r++) acc[i][j][r] = 0.f;

  const int srow = w * 32 + (lane >> 2);
  const int scol = (lane & 3) * 8;
  const u16* gB0 = W + (long)(n0 + srow) * ldb + scol;
  const u16* gB1 = gB0 + (long)16 * ldb;
  const int lo = w * 1024;
  const int r0 = tid >> 2, ch0 = (tid & 3) * 8;
  const float* F1 = Af + (long)(m0 + r0) * lda + ch0;
  const float* F2 = Af + (long)(m0 + r0 + 64) * lda + ch0;

  int cur = 0;
  {
    float4 p0 = *(const float4*)(F1);
    float4 p1 = *(const float4*)(F1 + 4);
    float4 q0 = *(const float4*)(F2);
    float4 q1 = *(const float4*)(F2 + 4);
    gload16(gB0, &Bs[0][lo]);
    gload16(gB1, &Bs[0][lo + 512]);
    *(uint4*)&As[0][r0 * 32 + ch0] = cvt8(p0, p1);
    *(uint4*)&As[0][(r0 + 64) * 32 + ch0] = cvt8(q0, q1);
  }
  __syncthreads();
  for (int k0 = 0; k0 < K; k0 += 32) {
    const int kn = k0 + 32;
    const bool more = kn < K;
    float4 p0, p1, q0, q1;
    if (more) {
      p0 = *(const float4*)(F1 + kn);
      p1 = *(const float4*)(F1 + kn + 4);
      q0 = *(const float4*)(F2 + kn);
      q1 = *(const float4*)(F2 + kn + 4);
      gload16(gB0 + kn, &Bs[cur ^ 1][lo]);
      gload16(gB1 + kn, &Bs[cur ^ 1][lo + 512]);
    }
    bf16x8 bfr[4];
    #pragma unroll
    for (int j = 0; j < 4; j++)
      bfr[j] = *(const bf16x8*)&Bs[cur][(wn + j * 16 + lr) * 32 + quad * 8];
    #pragma unroll
    for (int i = 0; i < 4; i++) {
      bf16x8 af = *(const bf16x8*)&As[cur][(wm + i * 16 + lr) * 32 + quad * 8];
      #pragma unroll
      for (int j = 0; j < 4; j++)
        acc[i][j] = MFMA16(af, bfr[j], acc[i][j]);
    }
    if (more) {
      *(uint4*)&As[cur ^ 1][r0 * 32 + ch0] = cvt8(p0, p1);
      *(uint4*)&As[cur ^ 1][(r0 + 64) * 32 + ch0] = cvt8(q0, q1);
    }
    __syncthreads();
    cur ^= 1;
  }

  #pragma unroll
  for (int i = 0; i < 4; i++) {
    #pragma unroll
    for (int j = 0; j < 4; j++) {
      #pragma unroll
      for (int r = 0; r < 4; r++) {
        const int gm = m0 + wm + i * 16 + quad * 4 + r;
        const int gn = n0 + wn + j * 16 + lr;
        float v = acc[i][j][r] + bias[gn];
        v = fmaxf(v, 0.f);
        float g2 = gates[(gm & 63) * 8 + (gn >> 6)];
        outB[(long)gm * N + gn] = f2bf(v * g2);
      }
    }
  }
}

// ---------------------------------------------------------------------------
// Fused attention per (b,h): S=QK^T/8 -> softmax -> P*V; O overwrites q-slot.
// qkv: [tok=l*64+b][3072], q@+0, k@+1024, v@+2048, col h*64+d. LDS ~51KB.
// ---------------------------------------------------------------------------
__global__ __launch_bounds__(256) void attn_k(u16* __restrict__ qkv)
{
  __shared__ u16 Vt[64 * 264];
  __shared__ u16 Ps[32 * 264];
  __shared__ float rowstat[64];
  float* red = (float*)Ps;  // red's lifetime ends before Ps is written
  const int bh = blockIdx.x, b = bh >> 4, h = bh & 15;
  const int tid = threadIdx.x, w = tid >> 6, lane = tid & 63;
  const int lr = lane & 15, quad = lane >> 4;
  const long base = (long)b * 3072 + h * 64;

  for (int c = tid; c < 2048; c += 256) {
    int m = c >> 3, ch = (c & 7) * 8;
    uint4 vv = *(const uint4*)(qkv + (long)m * 196608 + base + 2048 + ch);
    const u16* s = (const u16*)&vv;
    #pragma unroll
    for (int t = 0; t < 8; t++) Vt[(ch + t) * 264 + m] = s[t];
  }
  __syncthreads();

  for (int qb = 0; qb < 4; qb++) {
    f32x4 acc[4][4];
    #pragma unroll
    for (int i = 0; i < 4; i++)
      #pragma unroll
      for (int j = 0; j < 4; j++)
        #pragma unroll
        for (int r = 0; r < 4; r++) acc[i][j][r] = 0.f;

    #pragma unroll
    for (int ks = 0; ks < 2; ks++) {
      bf16x8 bfr[4];
      #pragma unroll
      for (int j = 0; j < 4; j++) {
        int key = w * 64 + j * 16 + lr;
        bfr[j] = *(const bf16x8*)(qkv + (long)key * 196608 + base + 1024 + ks * 32 + quad * 8);
      }
      #pragma unroll
      for (int i = 0; i < 4; i++) {
        int gq = qb * 64 + i * 16 + lr;
        bf16x8 af = *(const bf16x8*)(qkv + (long)gq * 196608 + base + ks * 32 + quad * 8);
        #pragma unroll
        for (int j = 0; j < 4; j++)
          acc[i][j] = MFMA16(af, bfr[j], acc[i][j]);
      }
    }

    #pragma unroll
    for (int i = 0; i < 4; i++) {
      #pragma unroll
      for (int r = 0; r < 4; r++) {
        float m = -1e30f;
        #pragma unroll
        for (int j = 0; j < 4; j++) {
          float s = acc[i][j][r] * 0.125f;
          acc[i][j][r] = s;
          m = fmaxf(m, s);
        }
        #pragma unroll
        for (int off = 1; off < 16; off <<= 1) m = fmaxf(m, __shfl_xor(m, off));
        if (lr == 0) red[w * 64 + i * 16 + quad * 4 + r] = m;
      }
    }
    __syncthreads();
    if (tid < 64)
      rowstat[tid] = fmaxf(fmaxf(red[tid], red[64 + tid]),
                           fmaxf(red[128 + tid], red[192 + tid]));
    __syncthreads();

    #pragma unroll
    for (int i = 0; i < 4; i++) {
      #pragma unroll
      for (int r = 0; r < 4; r++) {
        float rm = rowstat[i * 16 + quad * 4 + r];
        float s = 0.f;
        #pragma unroll
        for (int j = 0; j < 4; j++) {
          float e = __expf(acc[i][j][r] - rm);
          acc[i][j][r] = e;
          s += e;
        }
        #pragma unroll
        for (int off = 1; off < 16; off <<= 1) s += __shfl_xor(s, off);
        if (lr == 0) red[w * 64 + i * 16 + quad * 4 + r] = s;
      }
    }
    __syncthreads();
    if (tid < 64)
      rowstat[tid] = red[tid] + red[64 + tid] + red[128 + tid] + red[192 + tid];
    __syncthreads();

    #pragma unroll
    for (int hf = 0; hf < 2; hf++) {
      #pragma unroll
      for (int ii = 0; ii < 2; ii++) {
        int i = hf * 2 + ii;
        #pragma unroll
        for (int r = 0; r < 4; r++) {
          int row = i * 16 + quad * 4 + r;
          float inv = 1.f / rowstat[row];
          #pragma unroll
          for (int j = 0; j < 4; j++)
            Ps[(row - hf * 32) * 264 + w * 64 + j * 16 + lr] =
                f2bf(acc[i][j][r] * inv);
        }
      }
      __syncthreads();
      f32x4 o[2];
      #pragma unroll
      for (int j2 = 0; j2 < 2; j2++)
        #pragma unroll
        for (int r = 0; r < 4; r++) o[j2][r] = 0.f;
      #pragma unroll
      for (int ks = 0; ks < 8; ks++) {
        bf16x8 af = *(const bf16x8*)&Ps[((w >> 1) * 16 + lr) * 264 + ks * 32 + quad * 8];
        #pragma unroll
        for (int j2 = 0; j2 < 2; j2++) {
          int j = (w & 1) * 2 + j2;
          bf16x8 bv = *(const bf16x8*)&Vt[(j * 16 + lr) * 264 + ks * 32 + quad * 8];
          o[j2] = MFMA16(af, bv, o[j2]);
        }
      }
      int l0 = qb * 64 + hf * 32 + (w >> 1) * 16 + quad * 4;
      #pragma unroll
      for (int j2 = 0; j2 < 2; j2++) {
        int j = (w & 1) * 2 + j2;
        #pragma unroll
        for (int r = 0; r < 4; r++)
          qkv[(long)(l0 + r) * 196608 + base + j * 16 + lr] = f2bf(o[j2][r]);
      }
      __syncthreads();
    }
  }
}

// --------------------------- LayerNorm (f32 -> bf16) -----------------------
__global__ __launch_bounds__(256) void ln_k(const float* __restrict__ x,
                                            const float* __restrict__ wt,
                                            const float* __restrict__ bs,
                                            u16* __restrict__ out)
{
  const int tok = blockIdx.x * 4 + (threadIdx.x >> 6);
  const int lane = threadIdx.x & 63;
  const float* xp = x + (long)tok * 1024;
  float4 v[4];
  float s = 0.f, s2 = 0.f;
  #pragma unroll
  for (int t = 0; t < 4; t++) {
    v[t] = *(const float4*)(xp + t * 256 + lane * 4);
    s += v[t].x + v[t].y + v[t].z + v[t].w;
    s2 += v[t].x * v[t].x + v[t].y * v[t].y + v[t].z * v[t].z + v[t].w * v[t].w;
  }
  #pragma unroll
  for (int off = 32; off >= 1; off >>= 1) {
    s += __shfl_xor(s, off);
    s2 += __shfl_xor(s2, off);
  }
  const float m = s * (1.f / 1024.f);
  const float rstd = rsqrtf(s2 * (1.f / 1024.f) - m * m + 1e-5f);
  u16* op = out + (long)tok * 1024;
  #pragma unroll
  for (int t = 0; t < 4; t++) {
    int d = t * 256 + lane * 4;
    float4 wv = *(const float4*)(wt + d);
    float4 bv = *(const float4*)(bs + d);
    union { u16 h[4]; uint2 q; } o;
    o.h[0] = f2bf((v[t].x - m) * rstd * wv.x + bv.x);
    o.h[1] = f2bf((v[t].y - m) * rstd * wv.y + bv.y);
    o.h[2] = f2bf((v[t].z - m) * rstd * wv.z + bv.z);
    o.h[3] = f2bf((v[t].w - m) * rstd * wv.w + bv.w);
    *(uint2*)(op + d) = o.q;
  }
}

// --------------------------- weight converts -------------------------------
__global__ void cvtk(const float* __restrict__ src, u16* __restrict__ dst, int n4)
{
  int i = blockIdx.x * 256 + threadIdx.x;
  if (i >= n4) return;
  float4 v = ((const float4*)src)[i];
  union { u16 h[4]; uint2 q; } o;
  o.h[0] = f2bf(v.x); o.h[1] = f2bf(v.y); o.h[2] = f2bf(v.z); o.h[3] = f2bf(v.w);
  ((uint2*)dst)[i] = o.q;
}

// dst[d*512 + e*64 + r] = up_w[(e*1024 + d)*64 + r]   (up_w is (E,D,R))
__global__ void wupk(const float* __restrict__ up_w, u16* __restrict__ dst)
{
  int i = blockIdx.x * 256 + threadIdx.x;  // 524288
  int r = i & 63, e = (i >> 6) & 7, d = i >> 9;
  dst[i] = f2bf(up_w[(e * 1024 + d) * 64 + r]);
}

// --------------------------- gating ----------------------------------------
__global__ __launch_bounds__(256) void gate_k(const float* __restrict__ x1,
                                              const float* __restrict__ wg,
                                              float* __restrict__ gates)
{
  const int wv = threadIdx.x >> 6, lane = threadIdx.x & 63;
  const int b = blockIdx.x * 4 + wv;
  const float* xp = x1 + (long)b * 1024;
  float lg[8];
  #pragma unroll
  for (int e = 0; e < 8; e++) lg[e] = 0.f;
  for (int i = 0; i < 16; i++) {
    int d = i * 64 + lane;
    float xv = xp[d];
    #pragma unroll
    for (int e = 0; e < 8; e++) lg[e] += xv * wg[d * 8 + e];
  }
  #pragma unroll
  for (int e = 0; e < 8; e++)
    #pragma unroll
    for (int off = 32; off >= 1; off >>= 1) lg[e] += __shfl_xor(lg[e], off);
  if (lane == 0) {
    int e1 = 0; float v1 = lg[0];
    #pragma unroll
    for (int e = 1; e < 8; e++) if (lg[e] > v1) { v1 = lg[e]; e1 = e; }
    int e2 = -1; float v2 = -1e30f;
    #pragma unroll
    for (int e = 0; e < 8; e++) if (e != e1 && lg[e] > v2) { v2 = lg[e]; e2 = e; }
    float ex = __expf(v2 - v1);
    float inv = 1.f / (1.f + ex);
    #pragma unroll
    for (int e = 0; e < 8; e++)
      gates[b * 8 + e] = (e == e1) ? inv : ((e == e2) ? ex * inv : 0.f);
  }
}

__global__ void moe_loss_k(const float* __restrict__ gates, float* __restrict__ out)
{
  if (threadIdx.x != 0) return;
  float imp[8], ld[8];
  for (int e = 0; e < 8; e++) { imp[e] = 0.f; ld[e] = 0.f; }
  for (int b = 0; b < 64; b++)
    for (int e = 0; e < 8; e++) {
      float g = gates[b * 8 + e];
      imp[e] += g;
      if (g > 0.f) ld[e] += 1.f;
    }
  float mi = 0.f, ml = 0.f;
  for (int e = 0; e < 8; e++) { mi += imp[e]; ml += ld[e]; }
  mi *= 0.125f; ml *= 0.125f;
  float vi = 0.f, vl = 0.f;
  for (int e = 0; e < 8; e++) {
    float a = imp[e] - mi; vi += a * a;
    float c = ld[e] - ml; vl += c * c;
  }
  vi *= (1.f / 7.f); vl *= (1.f / 7.f);
  out[0] = 0.01f * (vi / (mi * mi + 1e-10f) + vl / (ml * ml + 1e-10f));
}

// gb[b][d] = sum_e gates[b,e] * up_b[e,d]
__global__ __launch_bounds__(256) void gb_k(const float* __restrict__ gates,
                                            const float* __restrict__ up_b,
                                            float* __restrict__ gb)
{
  int b = blockIdx.x, d0 = threadIdx.x * 4;
  float g[8];
  #pragma unroll
  for (int e = 0; e < 8; e++) g[e] = gates[b * 8 + e];
  float s0 = 0, s1 = 0, s2 = 0, s3 = 0;
  #pragma unroll
  for (int e = 0; e < 8; e++) {
    float4 u = *(const float4*)(up_b + e * 1024 + d0);
    s0 += g[e] * u.x; s1 += g[e] * u.y; s2 += g[e] * u.z; s3 += g[e] * u.w;
  }
  float4 r; r.x = s0; r.y = s1; r.z = s2; r.w = s3;
  *(float4*)(gb + b * 1024 + d0) = r;
}

// ---------------------------------------------------------------------------
extern "C" void kernel_launch(void* const* d_in, const int* in_sizes, int n_in,
                              void* d_out, int out_size, void* d_ws, size_t ws_size,
                              hipStream_t stream)
{
  (void)in_sizes; (void)n_in; (void)out_size;
  const float* x      = (const float*)d_in[0];
  const float* ln1_w  = (const float*)d_in[1];
  const float* ln1_b  = (const float*)d_in[2];
  const float* in_w   = (const float*)d_in[3];
  const float* in_b   = (const float*)d_in[4];
  const float* out_w  = (const float*)d_in[5];
  const float* out_b  = (const float*)d_in[6];
  const float* ln2_w  = (const float*)d_in[7];
  const float* ln2_b  = (const float*)d_in[8];
  const float* fc_w   = (const float*)d_in[9];
  const float* fc_b   = (const float*)d_in[10];
  const float* pj_w   = (const float*)d_in[11];
  const float* pj_b   = (const float*)d_in[12];
  const float* w_gate = (const float*)d_in[13];
  const float* down_w = (const float*)d_in[14];
  const float* down_b = (const float*)d_in[15];
  const float* up_w   = (const float*)d_in[16];
  const float* up_b   = (const float*)d_in[17];
  float* out = (float*)d_out;
  char* ws = (char*)d_ws;

  // ws layout (base footprint ~115 MB, proven), lifetime-aliased
  u16* wb_in   = (u16*)(ws + 0);          // 6 MB   (dead after qkv gemm)
  u16* wb_out  = (u16*)(ws + 6291456);    // 2 MB   (dead after out_proj)
  u16* wb_down = (u16*)(ws + 8388608);    // 1 MB
  u16* wb_up   = (u16*)(ws + 9437184);    // 1 MB
  u16* wb_fc   = (u16*)(ws + 0);          // 8 MB   (aliases in/out, converted late)
  u16* wb_pj   = (u16*)(ws + 10485760);   // 8 MB
  float* gates = (float*)(ws + 19005440); // 2 KB
  float* gb    = (float*)(ws + 19007488); // 256 KB
  u16* qkv     = (u16*)(ws + 19269632);   // 96 MB  (dead after out_proj)
  u16* xln2    = (u16*)(ws + 19269632);   // 32 MB  (alias qkv[0:32M])
  u16* hg      = (u16*)(ws + 52824064);   // 16 MB  (alias qkv[32M:48M])
  u16* h2      = (u16*)(ws + 69601280);   // 32 MB chunked / 128 MB if ws allows
  // xln (LN1 output, bf16) lives in d_out until out_proj overwrites it
  u16* xln = (u16*)d_out;

  const bool big = ws_size >= (size_t)203819008;  // 69601280 + 128 MB

  // phase-1 weight converts
  cvtk<<<3072, 256, 0, stream>>>(in_w, wb_in, 786432);
  cvtk<<<1024, 256, 0, stream>>>(out_w, wb_out, 262144);
  cvtk<<<512, 256, 0, stream>>>(down_w, wb_down, 131072);
  wupk<<<2048, 256, 0, stream>>>(up_w, wb_up);

  // LN1 -> xln (bf16, in d_out); qkv = xln @ in_w^T + in_b
  ln_k<<<4096, 256, 0, stream>>>(x, ln1_w, ln1_b, xln);
  gemm256_k<0><<<64 * 12, 512, 0, stream>>>(
      xln, 1024, wb_in, 1024, in_b, nullptr, nullptr, qkv, 3072, 1024);

  // fused attention; O overwrites q-slot of qkv
  attn_k<<<1024, 256, 0, stream>>>(qkv);

  // x1 = O @ out_w^T + out_b + x  -> d_out (f32)
  gemm256_k<1><<<64 * 4, 512, 0, stream>>>(
      qkv, 3072, wb_out, 1024, out_b, x, out, nullptr, 1024, 1024);

  // gating on x1 rows 0..63 (token 0 of each sequence)
  gate_k<<<16, 256, 0, stream>>>(out, w_gate, gates);
  moe_loss_k<<<1, 64, 0, stream>>>(gates, out + 16777216);
  gb_k<<<64, 256, 0, stream>>>(gates, up_b, gb);

  // LN2 must see pure x1 (before y accumulates into d_out)
  ln_k<<<4096, 256, 0, stream>>>(out, ln2_w, ln2_b, xln2);

  // adapter: down (relu, *gate) from f32 x1; up accumulates y into d_out
  gemm_down_k<<<4 * 128, 256, 0, stream>>>(
      out, 1024, wb_down, 1024, down_b, gates, hg, 512, 1024);
  gemm256_k<3><<<64 * 4, 512, 0, stream>>>(
      hg, 512, wb_up, 512, nullptr, gb, out, nullptr, 1024, 512);

  // phase-2 weight converts (overwrite dead phase-1 buffers)
  cvtk<<<4096, 256, 0, stream>>>(fc_w, wb_fc, 1048576);
  cvtk<<<4096, 256, 0, stream>>>(pj_w, wb_pj, 1048576);

  if (big) {
    // single-shot MLP: h2 = QuickGELU(xln2 @ fc_w^T + fc_b); out += h2 @ pj_w^T + pj_b
    gemm256_k<4><<<64 * 16, 512, 0, stream>>>(
        xln2, 1024, wb_fc, 1024, fc_b, nullptr, nullptr, h2, 4096, 1024);
    gemm256_k<5><<<64 * 4, 512, 0, stream>>>(
        h2, 4096, wb_pj, 4096, pj_b, nullptr, out, nullptr, 1024, 4096);
  } else {
    // 4 K-chunks (proven 115 MB footprint)
    for (int c = 0; c < 4; c++) {
      gemm256_k<4><<<64 * 4, 512, 0, stream>>>(
          xln2, 1024, wb_fc + (long)c * 1048576, 1024, fc_b + c * 1024,
          nullptr, nullptr, h2, 1024, 1024);
      gemm256_k<5><<<64 * 4, 512, 0, stream>>>(
          h2, 1024, wb_pj + c * 1024, 4096, (c == 0) ? pj_b : nullptr,
          nullptr, out, nullptr, 1024, 1024);
    }
  }
}

// Round 7
// 884.201 us; speedup vs baseline: 1.0495x; 1.0495x over previous
//
#include <hip/hip_runtime.h>

typedef unsigned short u16;
typedef unsigned int u32;
typedef __bf16 bf16x8 __attribute__((ext_vector_type(8)));
typedef float f32x4 __attribute__((ext_vector_type(4)));

#define MFMA16(a, b, c) __builtin_amdgcn_mfma_f32_16x16x32_bf16(a, b, c, 0, 0, 0)

__device__ __forceinline__ u16 f2bf(float f) {
  u32 u = __builtin_bit_cast(u32, f);
  u32 r = u + 0x7fffu + ((u >> 16) & 1u);
  return (u16)(r >> 16);
}

__device__ __forceinline__ uint4 cvt8(const float4& a, const float4& b) {
  union { u16 h[8]; uint4 q; } u;
  u.h[0] = f2bf(a.x); u.h[1] = f2bf(a.y); u.h[2] = f2bf(a.z); u.h[3] = f2bf(a.w);
  u.h[4] = f2bf(b.x); u.h[5] = f2bf(b.y); u.h[6] = f2bf(b.z); u.h[7] = f2bf(b.w);
  return u.q;
}

// async global->LDS, 16B per lane; lds dst is wave-uniform base + lane*16
__device__ __forceinline__ void gload16(const u16* g, u16* l) {
  __builtin_amdgcn_global_load_lds(
      (const __attribute__((address_space(1))) u32*)g,
      (__attribute__((address_space(3))) u32*)l, 16, 0, 0);
}

// memory-fenced raw barrier (s_barrier is NoMem in LLVM: fence both sides)
#define BARF() do { asm volatile("" ::: "memory"); \
                    __builtin_amdgcn_s_barrier();  \
                    asm volatile("" ::: "memory"); } while (0)

// ---------------------------------------------------------------------------
// 256x256-tile bf16 MFMA GEMM — round-7: 16 WAVES (1024 thr), wave tile
// 64x64, acc[4][4]=64 AGPR -> total regs <=128 -> 4 waves/SIMD (was 2).
// Rounds 4-6 post-mortem: three different intra-tile schedules all landed at
// 200us / 29% MfmaUtil -> schedule is not the limiter; with 1 block/CU and
// 236 unified regs capping occupancy at 2 waves/SIMD, per-wave stalls had no
// TLP cover. c_fc (same FLOPs, 4 blocks/CU) is measurably faster -> wave
// count is the separating variable. This kernel keeps the verified staging/
// swizzle/counted-vmcnt structure and only re-tiles waves.
// BK=64 K-tile, 4 phases/tile (khalf x ihalf), 8 MFMA/phase/wave.
// LDS [2 buf][2 khalf][256][32] u16 = 128 KB. Verified swizzle pair
// (0 conflicts measured): stage col scol=((l&3)^((l>>3)&3))*8, read at
// su=(quad^((lr>>1)&3))*8; LDS[r][s] holds global col-group s^((r>>1)&3).
// Staging: 16 waves x 16 rows = one 256x32 half-tile per gload16 round;
// per thread 4 loads/K-tile (A0,B0 at p0; A1,B1 at p2 -> next buffer).
// Counted vmcnt(2) at p1/p3 before the publishing barrier: every wave
// retires its own 2 oldest chunks pre-barrier, so all waves' DMA for the
// next phase's reads is landed at barrier-cross. Ledger (steady): enter
// tile t with [tA1,tB1]; p0 issues t+1A0,B0; p1 vmcnt(2) retires tA1,tB1
// (read at p2); p2 issues t+1A1,B1; p3 vmcnt(2) retires t+1A0,B0 (read at
// t+1 p0). Chunks fly >=3 phases (~1900cy) >> 900cy HBM latency.
// Grid: 64 M-blocks x (N/256), groups of 16 M-blocks (A-sharers same XCD).
// C = A(MxK, lda) * W(NxK, ldb)^T, fused epilogues:
// MODE 0: +bias, store bf16               (qkv)
// MODE 1: +bias +aux0(x f32), store f32   (out_proj -> x1 in d_out)
// MODE 3: outF += 0.1*(acc + gb)          (adapter up -> y into d_out)
// MODE 4: +bias, QuickGELU, bf16          (c_fc -> h2)
// MODE 5: outF += acc (+bias if given)    (c_proj into d_out)
// ---------------------------------------------------------------------------
template <int MODE>
__global__ __launch_bounds__(1024, 4) void gemm256_k(
    const u16* __restrict__ A, int lda,
    const u16* __restrict__ W, int ldb,
    const float* __restrict__ bias, const float* __restrict__ aux0,
    float* __restrict__ outF, u16* __restrict__ outB, int N, int K)
{
  __shared__ u16 As[2][2][8192];   // [buf][khalf][256 rows x 32 cols]
  __shared__ u16 Bs[2][2][8192];
  const int tid = threadIdx.x;
  const int nxb = N >> 8;
  const int gsz = nxb << 4;               // 16 M-blocks per group
  const int g = blockIdx.x / gsz;
  const int rem = blockIdx.x - g * gsz;
  const int m0 = ((g << 4) + (rem & 15)) * 256;
  const int n0 = (rem >> 4) * 256;
  const int w = tid >> 6, lane = tid & 63, lr = lane & 15, quad = lane >> 4;
  const int wr = (w >> 2) * 64, wc = (w & 3) * 64;   // 4x4 wave grid

  f32x4 acc[4][4];
  #pragma unroll
  for (int i = 0; i < 4; i++)
    #pragma unroll
    for (int j = 0; j < 4; j++)
      #pragma unroll
      for (int r = 0; r < 4; r++) acc[i][j][r] = 0.f;

  // staging: wave w covers rows w*16..w*16+15 of each 256x32 half-tile;
  // one gload16 per thread per half-tile. Verified swizzle (rounds 3-6).
  const int sr = w * 16 + (lane >> 2);
  const int scol = ((lane & 3) ^ ((lane >> 3) & 3)) * 8;
  const u16* gA0 = A + (long)(m0 + sr) * lda + scol;
  const u16* gB0 = W + (long)(n0 + sr) * ldb + scol;
  const int lo = w << 9;                  // wave-uniform LDS base (u16)
  const int su = (quad ^ ((lr >> 1) & 3)) * 8;   // read-side swizzled slot

  auto rdA2 = [&](bf16x8* af, const u16* tile, int ih) {
    #pragma unroll
    for (int i2 = 0; i2 < 2; i2++)
      af[i2] = *(const bf16x8*)&tile[(wr + ih * 32 + i2 * 16 + lr) * 32 + su];
  };
  auto rdB4 = [&](bf16x8* bb, const u16* tile) {
    #pragma unroll
    for (int j = 0; j < 4; j++)
      bb[j] = *(const bf16x8*)&tile[(wc + j * 16 + lr) * 32 + su];
  };
  auto mm8 = [&](int ih, bf16x8* af, bf16x8* bb) {
    __builtin_amdgcn_s_setprio(1);
    #pragma unroll
    for (int i2 = 0; i2 < 2; i2++)
      #pragma unroll
      for (int j = 0; j < 4; j++)
        acc[ih * 2 + i2][j] = MFMA16(af[i2], bb[j], acc[ih * 2 + i2][j]);
    __builtin_amdgcn_s_setprio(0);
  };

  const int nt = K >> 6;                  // K-tiles of 64; >= 8 at all sites

  // prologue: stage K-tile 0 (4 chunks, 1 load/thread each), drain, publish
  gload16(gA0,      As[0][0] + lo);
  gload16(gB0,      Bs[0][0] + lo);
  gload16(gA0 + 32, As[0][1] + lo);
  gload16(gB0 + 32, Bs[0][1] + lo);
  asm volatile("s_waitcnt vmcnt(0)" ::: "memory");
  __syncthreads();

  for (int t = 0; t < nt; ++t) {
    const int cur = t & 1, nb = cur ^ 1;
    const bool more = (t + 1) < nt;
    const long kb = (long)(t + 1) * 64;
    const u16* A0 = As[cur][0]; const u16* A1 = As[cur][1];
    const u16* B0 = Bs[cur][0]; const u16* B1 = Bs[cur][1];
    bf16x8 af[2], bb[4];
    // ---- p0: (k0, ih0) ---- (tile-t k0 chunks retired before prev barrier)
    rdB4(bb, B0); rdA2(af, A0, 0);
    if (more) {
      gload16(gA0 + kb, As[nb][0] + lo);
      gload16(gB0 + kb, Bs[nb][0] + lo);
    }
    BARF(); mm8(0, af, bb);
    // ---- p1: (k0, ih1) ---- retire THIS tile's k1 chunks pre-barrier
    rdA2(af, A0, 1);
    if (more) asm volatile("s_waitcnt vmcnt(2)" ::: "memory");
    else      asm volatile("s_waitcnt vmcnt(0)" ::: "memory");
    BARF(); mm8(1, af, bb);
    // ---- p2: (k1, ih0) ----
    rdB4(bb, B1); rdA2(af, A1, 0);
    if (more) {
      gload16(gA0 + kb + 32, As[nb][1] + lo);
      gload16(gB0 + kb + 32, Bs[nb][1] + lo);
    }
    BARF(); mm8(0, af, bb);
    // ---- p3: (k1, ih1) ---- retire NEXT tile's k0 chunks pre-barrier
    rdA2(af, A1, 1);
    if (more) asm volatile("s_waitcnt vmcnt(2)" ::: "memory");
    BARF(); mm8(1, af, bb);
  }

  #pragma unroll
  for (int i = 0; i < 4; i++) {
    #pragma unroll
    for (int j = 0; j < 4; j++) {
      #pragma unroll
      for (int r = 0; r < 4; r++) {
        const int gm = m0 + wr + i * 16 + quad * 4 + r;
        const int gn = n0 + wc + j * 16 + lr;
        const long oidx = (long)gm * N + gn;
        float v = acc[i][j][r];
        if constexpr (MODE == 0) {
          v += bias[gn];
          outB[oidx] = f2bf(v);
        } else if constexpr (MODE == 1) {
          v += bias[gn] + aux0[oidx];
          outF[oidx] = v;
        } else if constexpr (MODE == 3) {
          outF[oidx] += 0.1f * (v + aux0[(gm & 63) * 1024 + gn]);
        } else if constexpr (MODE == 4) {
          v += bias[gn];
          float e = __expf(-1.702f * v);
          v = v * __builtin_amdgcn_rcpf(1.f + e);
          outB[oidx] = f2bf(v);
        } else {
          if (bias) v += bias[gn];
          outF[oidx] += v;
        }
      }
    }
  }
}

// ---------------------------------------------------------------------------
// Adapter-down GEMM (proven round-1/2 path): 128x128 tile, A f32 convert-in-
// staging, relu + gate epilogue. Small (N=512, K=1024) — not worth porting.
// ---------------------------------------------------------------------------
__global__ __launch_bounds__(256) void gemm_down_k(
    const float* __restrict__ Af, int lda,
    const u16* __restrict__ W, int ldb,
    const float* __restrict__ bias, const float* __restrict__ gates,
    u16* __restrict__ outB, int N, int K)
{
  __shared__ u16 As[2][128 * 32];
  __shared__ u16 Bs[2][128 * 32];
  const int tid = threadIdx.x;
  const int nxb = gridDim.x >> 7;
  const int gsz = nxb << 5;
  const int g = blockIdx.x / gsz;
  const int rem = blockIdx.x - g * gsz;
  const int m0 = ((g << 5) + (rem & 31)) * 128;
  const int n0 = (rem >> 5) * 128;
  const int w = tid >> 6, lane = tid & 63, lr = lane & 15, quad = lane >> 4;
  const int wm = (w >> 1) * 64, wn = (w & 1) * 64;

  f32x4 acc[4][4];
  #pragma unroll
  for (int i = 0; i < 4; i++)
    #pragma unroll
    for (int j = 0; j < 4; j++)
      #pragma unroll
      for (int r = 0; r < 4; r++) acc[i][j][r] = 0.f;

  const int srow = w * 32 + (lane >> 2);
  const int scol = (lane & 3) * 8;
  const u16* gB0 = W + (long)(n0 + srow) * ldb + scol;
  const u16* gB1 = gB0 + (long)16 * ldb;
  const int lo = w * 1024;
  const int r0 = tid >> 2, ch0 = (tid & 3) * 8;
  const float* F1 = Af + (long)(m0 + r0) * lda + ch0;
  const float* F2 = Af + (long)(m0 + r0 + 64) * lda + ch0;

  int cur = 0;
  {
    float4 p0 = *(const float4*)(F1);
    float4 p1 = *(const float4*)(F1 + 4);
    float4 q0 = *(const float4*)(F2);
    float4 q1 = *(const float4*)(F2 + 4);
    gload16(gB0, &Bs[0][lo]);
    gload16(gB1, &Bs[0][lo + 512]);
    *(uint4*)&As[0][r0 * 32 + ch0] = cvt8(p0, p1);
    *(uint4*)&As[0][(r0 + 64) * 32 + ch0] = cvt8(q0, q1);
  }
  __syncthreads();
  for (int k0 = 0; k0 < K; k0 += 32) {
    const int kn = k0 + 32;
    const bool more = kn < K;
    float4 p0, p1, q0, q1;
    if (more) {
      p0 = *(const float4*)(F1 + kn);
      p1 = *(const float4*)(F1 + kn + 4);
      q0 = *(const float4*)(F2 + kn);
      q1 = *(const float4*)(F2 + kn + 4);
      gload16(gB0 + kn, &Bs[cur ^ 1][lo]);
      gload16(gB1 + kn, &Bs[cur ^ 1][lo + 512]);
    }
    bf16x8 bfr[4];
    #pragma unroll
    for (int j = 0; j < 4; j++)
      bfr[j] = *(const bf16x8*)&Bs[cur][(wn + j * 16 + lr) * 32 + quad * 8];
    #pragma unroll
    for (int i = 0; i < 4; i++) {
      bf16x8 af = *(const bf16x8*)&As[cur][(wm + i * 16 + lr) * 32 + quad * 8];
      #pragma unroll
      for (int j = 0; j < 4; j++)
        acc[i][j] = MFMA16(af, bfr[j], acc[i][j]);
    }
    if (more) {
      *(uint4*)&As[cur ^ 1][r0 * 32 + ch0] = cvt8(p0, p1);
      *(uint4*)&As[cur ^ 1][(r0 + 64) * 32 + ch0] = cvt8(q0, q1);
    }
    __syncthreads();
    cur ^= 1;
  }

  #pragma unroll
  for (int i = 0; i < 4; i++) {
    #pragma unroll
    for (int j = 0; j < 4; j++) {
      #pragma unroll
      for (int r = 0; r < 4; r++) {
        const int gm = m0 + wm + i * 16 + quad * 4 + r;
        const int gn = n0 + wn + j * 16 + lr;
        float v = acc[i][j][r] + bias[gn];
        v = fmaxf(v, 0.f);
        float g2 = gates[(gm & 63) * 8 + (gn >> 6)];
        outB[(long)gm * N + gn] = f2bf(v * g2);
      }
    }
  }
}

// ---------------------------------------------------------------------------
// Fused attention per (b,h): S=QK^T/8 -> softmax -> P*V; O overwrites q-slot.
// qkv: [tok=l*64+b][3072], q@+0, k@+1024, v@+2048, col h*64+d. LDS ~51KB.
// ---------------------------------------------------------------------------
__global__ __launch_bounds__(256) void attn_k(u16* __restrict__ qkv)
{
  __shared__ u16 Vt[64 * 264];
  __shared__ u16 Ps[32 * 264];
  __shared__ float rowstat[64];
  float* red = (float*)Ps;  // red's lifetime ends before Ps is written
  const int bh = blockIdx.x, b = bh >> 4, h = bh & 15;
  const int tid = threadIdx.x, w = tid >> 6, lane = tid & 63;
  const int lr = lane & 15, quad = lane >> 4;
  const long base = (long)b * 3072 + h * 64;

  for (int c = tid; c < 2048; c += 256) {
    int m = c >> 3, ch = (c & 7) * 8;
    uint4 vv = *(const uint4*)(qkv + (long)m * 196608 + base + 2048 + ch);
    const u16* s = (const u16*)&vv;
    #pragma unroll
    for (int t = 0; t < 8; t++) Vt[(ch + t) * 264 + m] = s[t];
  }
  __syncthreads();

  for (int qb = 0; qb < 4; qb++) {
    f32x4 acc[4][4];
    #pragma unroll
    for (int i = 0; i < 4; i++)
      #pragma unroll
      for (int j = 0; j < 4; j++)
        #pragma unroll
        for (int r = 0; r < 4; r++) acc[i][j][r] = 0.f;

    #pragma unroll
    for (int ks = 0; ks < 2; ks++) {
      bf16x8 bfr[4];
      #pragma unroll
      for (int j = 0; j < 4; j++) {
        int key = w * 64 + j * 16 + lr;
        bfr[j] = *(const bf16x8*)(qkv + (long)key * 196608 + base + 1024 + ks * 32 + quad * 8);
      }
      #pragma unroll
      for (int i = 0; i < 4; i++) {
        int gq = qb * 64 + i * 16 + lr;
        bf16x8 af = *(const bf16x8*)(qkv + (long)gq * 196608 + base + ks * 32 + quad * 8);
        #pragma unroll
        for (int j = 0; j < 4; j++)
          acc[i][j] = MFMA16(af, bfr[j], acc[i][j]);
      }
    }

    #pragma unroll
    for (int i = 0; i < 4; i++) {
      #pragma unroll
      for (int r = 0; r < 4; r++) {
        float m = -1e30f;
        #pragma unroll
        for (int j = 0; j < 4; j++) {
          float s = acc[i][j][r] * 0.125f;
          acc[i][j][r] = s;
          m = fmaxf(m, s);
        }
        #pragma unroll
        for (int off = 1; off < 16; off <<= 1) m = fmaxf(m, __shfl_xor(m, off));
        if (lr == 0) red[w * 64 + i * 16 + quad * 4 + r] = m;
      }
    }
    __syncthreads();
    if (tid < 64)
      rowstat[tid] = fmaxf(fmaxf(red[tid], red[64 + tid]),
                           fmaxf(red[128 + tid], red[192 + tid]));
    __syncthreads();

    #pragma unroll
    for (int i = 0; i < 4; i++) {
      #pragma unroll
      for (int r = 0; r < 4; r++) {
        float rm = rowstat[i * 16 + quad * 4 + r];
        float s = 0.f;
        #pragma unroll
        for (int j = 0; j < 4; j++) {
          float e = __expf(acc[i][j][r] - rm);
          acc[i][j][r] = e;
          s += e;
        }
        #pragma unroll
        for (int off = 1; off < 16; off <<= 1) s += __shfl_xor(s, off);
        if (lr == 0) red[w * 64 + i * 16 + quad * 4 + r] = s;
      }
    }
    __syncthreads();
    if (tid < 64)
      rowstat[tid] = red[tid] + red[64 + tid] + red[128 + tid] + red[192 + tid];
    __syncthreads();

    #pragma unroll
    for (int hf = 0; hf < 2; hf++) {
      #pragma unroll
      for (int ii = 0; ii < 2; ii++) {
        int i = hf * 2 + ii;
        #pragma unroll
        for (int r = 0; r < 4; r++) {
          int row = i * 16 + quad * 4 + r;
          float inv = 1.f / rowstat[row];
          #pragma unroll
          for (int j = 0; j < 4; j++)
            Ps[(row - hf * 32) * 264 + w * 64 + j * 16 + lr] =
                f2bf(acc[i][j][r] * inv);
        }
      }
      __syncthreads();
      f32x4 o[2];
      #pragma unroll
      for (int j2 = 0; j2 < 2; j2++)
        #pragma unroll
        for (int r = 0; r < 4; r++) o[j2][r] = 0.f;
      #pragma unroll
      for (int ks = 0; ks < 8; ks++) {
        bf16x8 af = *(const bf16x8*)&Ps[((w >> 1) * 16 + lr) * 264 + ks * 32 + quad * 8];
        #pragma unroll
        for (int j2 = 0; j2 < 2; j2++) {
          int j = (w & 1) * 2 + j2;
          bf16x8 bv = *(const bf16x8*)&Vt[(j * 16 + lr) * 264 + ks * 32 + quad * 8];
          o[j2] = MFMA16(af, bv, o[j2]);
        }
      }
      int l0 = qb * 64 + hf * 32 + (w >> 1) * 16 + quad * 4;
      #pragma unroll
      for (int j2 = 0; j2 < 2; j2++) {
        int j = (w & 1) * 2 + j2;
        #pragma unroll
        for (int r = 0; r < 4; r++)
          qkv[(long)(l0 + r) * 196608 + base + j * 16 + lr] = f2bf(o[j2][r]);
      }
      __syncthreads();
    }
  }
}

// --------------------------- LayerNorm (f32 -> bf16) -----------------------
__global__ __launch_bounds__(256) void ln_k(const float* __restrict__ x,
                                            const float* __restrict__ wt,
                                            const float* __restrict__ bs,
                                            u16* __restrict__ out)
{
  const int tok = blockIdx.x * 4 + (threadIdx.x >> 6);
  const int lane = threadIdx.x & 63;
  const float* xp = x + (long)tok * 1024;
  float4 v[4];
  float s = 0.f, s2 = 0.f;
  #pragma unroll
  for (int t = 0; t < 4; t++) {
    v[t] = *(const float4*)(xp + t * 256 + lane * 4);
    s += v[t].x + v[t].y + v[t].z + v[t].w;
    s2 += v[t].x * v[t].x + v[t].y * v[t].y + v[t].z * v[t].z + v[t].w * v[t].w;
  }
  #pragma unroll
  for (int off = 32; off >= 1; off >>= 1) {
    s += __shfl_xor(s, off);
    s2 += __shfl_xor(s2, off);
  }
  const float m = s * (1.f / 1024.f);
  const float rstd = rsqrtf(s2 * (1.f / 1024.f) - m * m + 1e-5f);
  u16* op = out + (long)tok * 1024;
  #pragma unroll
  for (int t = 0; t < 4; t++) {
    int d = t * 256 + lane * 4;
    float4 wv = *(const float4*)(wt + d);
    float4 bv = *(const float4*)(bs + d);
    union { u16 h[4]; uint2 q; } o;
    o.h[0] = f2bf((v[t].x - m) * rstd * wv.x + bv.x);
    o.h[1] = f2bf((v[t].y - m) * rstd * wv.y + bv.y);
    o.h[2] = f2bf((v[t].z - m) * rstd * wv.z + bv.z);
    o.h[3] = f2bf((v[t].w - m) * rstd * wv.w + bv.w);
    *(uint2*)(op + d) = o.q;
  }
}

// --------------------------- weight converts -------------------------------
__global__ void cvtk(const float* __restrict__ src, u16* __restrict__ dst, int n4)
{
  int i = blockIdx.x * 256 + threadIdx.x;
  if (i >= n4) return;
  float4 v = ((const float4*)src)[i];
  union { u16 h[4]; uint2 q; } o;
  o.h[0] = f2bf(v.x); o.h[1] = f2bf(v.y); o.h[2] = f2bf(v.z); o.h[3] = f2bf(v.w);
  ((uint2*)dst)[i] = o.q;
}

// dst[d*512 + e*64 + r] = up_w[(e*1024 + d)*64 + r]   (up_w is (E,D,R))
__global__ void wupk(const float* __restrict__ up_w, u16* __restrict__ dst)
{
  int i = blockIdx.x * 256 + threadIdx.x;  // 524288
  int r = i & 63, e = (i >> 6) & 7, d = i >> 9;
  dst[i] = f2bf(up_w[(e * 1024 + d) * 64 + r]);
}

// --------------------------- gating ----------------------------------------
__global__ __launch_bounds__(256) void gate_k(const float* __restrict__ x1,
                                              const float* __restrict__ wg,
                                              float* __restrict__ gates)
{
  const int wv = threadIdx.x >> 6, lane = threadIdx.x & 63;
  const int b = blockIdx.x * 4 + wv;
  const float* xp = x1 + (long)b * 1024;
  float lg[8];
  #pragma unroll
  for (int e = 0; e < 8; e++) lg[e] = 0.f;
  for (int i = 0; i < 16; i++) {
    int d = i * 64 + lane;
    float xv = xp[d];
    #pragma unroll
    for (int e = 0; e < 8; e++) lg[e] += xv * wg[d * 8 + e];
  }
  #pragma unroll
  for (int e = 0; e < 8; e++)
    #pragma unroll
    for (int off = 32; off >= 1; off >>= 1) lg[e] += __shfl_xor(lg[e], off);
  if (lane == 0) {
    int e1 = 0; float v1 = lg[0];
    #pragma unroll
    for (int e = 1; e < 8; e++) if (lg[e] > v1) { v1 = lg[e]; e1 = e; }
    int e2 = -1; float v2 = -1e30f;
    #pragma unroll
    for (int e = 0; e < 8; e++) if (e != e1 && lg[e] > v2) { v2 = lg[e]; e2 = e; }
    float ex = __expf(v2 - v1);
    float inv = 1.f / (1.f + ex);
    #pragma unroll
    for (int e = 0; e < 8; e++)
      gates[b * 8 + e] = (e == e1) ? inv : ((e == e2) ? ex * inv : 0.f);
  }
}

__global__ void moe_loss_k(const float* __restrict__ gates, float* __restrict__ out)
{
  if (threadIdx.x != 0) return;
  float imp[8], ld[8];
  for (int e = 0; e < 8; e++) { imp[e] = 0.f; ld[e] = 0.f; }
  for (int b = 0; b < 64; b++)
    for (int e = 0; e < 8; e++) {
      float g = gates[b * 8 + e];
      imp[e] += g;
      if (g > 0.f) ld[e] += 1.f;
    }
  float mi = 0.f, ml = 0.f;
  for (int e = 0; e < 8; e++) { mi += imp[e]; ml += ld[e]; }
  mi *= 0.125f; ml *= 0.125f;
  float vi = 0.f, vl = 0.f;
  for (int e = 0; e < 8; e++) {
    float a = imp[e] - mi; vi += a * a;
    float c = ld[e] - ml; vl += c * c;
  }
  vi *= (1.f / 7.f); vl *= (1.f / 7.f);
  out[0] = 0.01f * (vi / (mi * mi + 1e-10f) + vl / (ml * ml + 1e-10f));
}

// gb[b][d] = sum_e gates[b,e] * up_b[e,d]
__global__ __launch_bounds__(256) void gb_k(const float* __restrict__ gates,
                                            const float* __restrict__ up_b,
                                            float* __restrict__ gb)
{
  int b = blockIdx.x, d0 = threadIdx.x * 4;
  float g[8];
  #pragma unroll
  for (int e = 0; e < 8; e++) g[e] = gates[b * 8 + e];
  float s0 = 0, s1 = 0, s2 = 0, s3 = 0;
  #pragma unroll
  for (int e = 0; e < 8; e++) {
    float4 u = *(const float4*)(up_b + e * 1024 + d0);
    s0 += g[e] * u.x; s1 += g[e] * u.y; s2 += g[e] * u.z; s3 += g[e] * u.w;
  }
  float4 r; r.x = s0; r.y = s1; r.z = s2; r.w = s3;
  *(float4*)(gb + b * 1024 + d0) = r;
}

// ---------------------------------------------------------------------------
extern "C" void kernel_launch(void* const* d_in, const int* in_sizes, int n_in,
                              void* d_out, int out_size, void* d_ws, size_t ws_size,
                              hipStream_t stream)
{
  (void)in_sizes; (void)n_in; (void)out_size;
  const float* x      = (const float*)d_in[0];
  const float* ln1_w  = (const float*)d_in[1];
  const float* ln1_b  = (const float*)d_in[2];
  const float* in_w   = (const float*)d_in[3];
  const float* in_b   = (const float*)d_in[4];
  const float* out_w  = (const float*)d_in[5];
  const float* out_b  = (const float*)d_in[6];
  const float* ln2_w  = (const float*)d_in[7];
  const float* ln2_b  = (const float*)d_in[8];
  const float* fc_w   = (const float*)d_in[9];
  const float* fc_b   = (const float*)d_in[10];
  const float* pj_w   = (const float*)d_in[11];
  const float* pj_b   = (const float*)d_in[12];
  const float* w_gate = (const float*)d_in[13];
  const float* down_w = (const float*)d_in[14];
  const float* down_b = (const float*)d_in[15];
  const float* up_w   = (const float*)d_in[16];
  const float* up_b   = (const float*)d_in[17];
  float* out = (float*)d_out;
  char* ws = (char*)d_ws;

  // ws layout (base footprint ~115 MB, proven), lifetime-aliased
  u16* wb_in   = (u16*)(ws + 0);          // 6 MB   (dead after qkv gemm)
  u16* wb_out  = (u16*)(ws + 6291456);    // 2 MB   (dead after out_proj)
  u16* wb_down = (u16*)(ws + 8388608);    // 1 MB
  u16* wb_up   = (u16*)(ws + 9437184);    // 1 MB
  u16* wb_fc   = (u16*)(ws + 0);          // 8 MB   (aliases in/out, converted late)
  u16* wb_pj   = (u16*)(ws + 10485760);   // 8 MB
  float* gates = (float*)(ws + 19005440); // 2 KB
  float* gb    = (float*)(ws + 19007488); // 256 KB
  u16* qkv     = (u16*)(ws + 19269632);   // 96 MB  (dead after out_proj)
  u16* xln2    = (u16*)(ws + 19269632);   // 32 MB  (alias qkv[0:32M])
  u16* hg      = (u16*)(ws + 52824064);   // 16 MB  (alias qkv[32M:48M])
  u16* h2      = (u16*)(ws + 69601280);   // 32 MB chunked / 128 MB if ws allows
  // xln (LN1 output, bf16) lives in d_out until out_proj overwrites it
  u16* xln = (u16*)d_out;

  const bool big = ws_size >= (size_t)203819008;  // 69601280 + 128 MB

  // phase-1 weight converts
  cvtk<<<3072, 256, 0, stream>>>(in_w, wb_in, 786432);
  cvtk<<<1024, 256, 0, stream>>>(out_w, wb_out, 262144);
  cvtk<<<512, 256, 0, stream>>>(down_w, wb_down, 131072);
  wupk<<<2048, 256, 0, stream>>>(up_w, wb_up);

  // LN1 -> xln (bf16, in d_out); qkv = xln @ in_w^T + in_b
  ln_k<<<4096, 256, 0, stream>>>(x, ln1_w, ln1_b, xln);
  gemm256_k<0><<<64 * 12, 1024, 0, stream>>>(
      xln, 1024, wb_in, 1024, in_b, nullptr, nullptr, qkv, 3072, 1024);

  // fused attention; O overwrites q-slot of qkv
  attn_k<<<1024, 256, 0, stream>>>(qkv);

  // x1 = O @ out_w^T + out_b + x  -> d_out (f32)
  gemm256_k<1><<<64 * 4, 1024, 0, stream>>>(
      qkv, 3072, wb_out, 1024, out_b, x, out, nullptr, 1024, 1024);

  // gating on x1 rows 0..63 (token 0 of each sequence)
  gate_k<<<16, 256, 0, stream>>>(out, w_gate, gates);
  moe_loss_k<<<1, 64, 0, stream>>>(gates, out + 16777216);
  gb_k<<<64, 256, 0, stream>>>(gates, up_b, gb);

  // LN2 must see pure x1 (before y accumulates into d_out)
  ln_k<<<4096, 256, 0, stream>>>(out, ln2_w, ln2_b, xln2);

  // adapter: down (relu, *gate) from f32 x1; up accumulates y into d_out
  gemm_down_k<<<4 * 128, 256, 0, stream>>>(
      out, 1024, wb_down, 1024, down_b, gates, hg, 512, 1024);
  gemm256_k<3><<<64 * 4, 1024, 0, stream>>>(
      hg, 512, wb_up, 512, nullptr, gb, out, nullptr, 1024, 512);

  // phase-2 weight converts (overwrite dead phase-1 buffers)
  cvtk<<<4096, 256, 0, stream>>>(fc_w, wb_fc, 1048576);
  cvtk<<<4096, 256, 0, stream>>>(pj_w, wb_pj, 1048576);

  if (big) {
    // single-shot MLP: h2 = QuickGELU(xln2 @ fc_w^T + fc_b); out += h2 @ pj_w^T + pj_b
    gemm256_k<4><<<64 * 16, 1024, 0, stream>>>(
        xln2, 1024, wb_fc, 1024, fc_b, nullptr, nullptr, h2, 4096, 1024);
    gemm256_k<5><<<64 * 4, 1024, 0, stream>>>(
        h2, 4096, wb_pj, 4096, pj_b, nullptr, out, nullptr, 1024, 4096);
  } else {
    // 4 K-chunks (proven 115 MB footprint)
    for (int c = 0; c < 4; c++) {
      gemm256_k<4><<<64 * 4, 1024, 0, stream>>>(
          xln2, 1024, wb_fc + (long)c * 1048576, 1024, fc_b + c * 1024,
          nullptr, nullptr, h2, 1024, 1024);
      gemm256_k<5><<<64 * 4, 1024, 0, stream>>>(
          h2, 1024, wb_pj + c * 1024, 4096, (c == 0) ? pj_b : nullptr,
          nullptr, out, nullptr, 1024, 1024);
    }
  }
}